// Round 7
// baseline (363.780 us; speedup 1.0000x reference)
//
#include <hip/hip_runtime.h>
#include <hip/hip_bf16.h>
#include <stdint.h>

#define BB   8
#define LSEQ 4096
#define HH   512
#define KIN  10
#define NC   64
#define CHK  64        // LSEQ / NC

// f32 output layout (elements): t_enc [0, 262144), h_fwd [262144, +B*L*H), h_bwd next
#define OUT_TENC_N (BB*LSEQ*8)            // 262144
#define HSIZE      ((size_t)BB*LSEQ*HH)   // 16777216 per direction

// ws layout (floats):
//   [0, 20480)     Weff[4][KIN][HH]   m: 0=f_z 1=f_h 2=b_z 3=b_h
//   [20480,22528)  beff[4][HH]
//   sums:          sumG[2][BB][NC][HH], sumP[2][BB][NC][HH]
#define WOFF_WEFF 0
#define WOFF_BEFF 20480
#define WOFF_SG   22528
#define WOFF_SP   (22528 + 2*BB*NC*HH)
#define WS_FLOATS (22528 + 4*BB*NC*HH)    // 4.28 MB

// ---------------- compose: Weff[m] = proj_w @ W (K=10 effective), beff[m] = proj_b @ W + b
__global__ __launch_bounds__(512)
void compose_kernel(const float* __restrict__ fproj_w, const float* __restrict__ fproj_b,
                    const float* __restrict__ bproj_w, const float* __restrict__ bproj_b,
                    const float* __restrict__ f_wz, const float* __restrict__ f_bz,
                    const float* __restrict__ f_wh, const float* __restrict__ f_bh,
                    const float* __restrict__ b_wz, const float* __restrict__ b_bz,
                    const float* __restrict__ b_wh, const float* __restrict__ b_bh,
                    float* __restrict__ ws) {
    int m = blockIdx.x;          // 0=f_z 1=f_h 2=b_z 3=b_h
    int j = threadIdx.x;         // 0..511
    const float* P  = (m < 2) ? fproj_w : bproj_w;
    const float* pb = (m < 2) ? fproj_b : bproj_b;
    const float* W; const float* wb;
    if (m == 0)      { W = f_wz; wb = f_bz; }
    else if (m == 1) { W = f_wh; wb = f_bh; }
    else if (m == 2) { W = b_wz; wb = b_bz; }
    else             { W = b_wh; wb = b_bh; }

    float acc[KIN];
    #pragma unroll
    for (int i = 0; i < KIN; i++) acc[i] = 0.f;
    float accb = wb[j];
    for (int k = 0; k < HH; k++) {
        float w = W[k*HH + j];                   // coalesced
        accb = fmaf(pb[k], w, accb);             // uniform broadcast
        #pragma unroll
        for (int i = 0; i < KIN; i++) acc[i] = fmaf(P[i*HH + k], w, acc[i]);
    }
    #pragma unroll
    for (int i = 0; i < KIN; i++) ws[WOFF_WEFF + (m*KIN + i)*HH + j] = acc[i];
    ws[WOFF_BEFF + m*HH + j] = accb;
}

// ---------------- t_enc (f32 out)
__global__ __launch_bounds__(256)
void tenc_kernel(const float* __restrict__ t,
                 const float* __restrict__ te_w1, const float* __restrict__ te_b1,
                 const float* __restrict__ te_w2, const float* __restrict__ te_b2,
                 float* __restrict__ out) {
    int idx = blockIdx.x * 256 + threadIdx.x;    // b*L + l
    int b = idx >> 12;                           // L = 4096
    float ts = t[idx] - t[(size_t)b << 12];

    float h1[8];
    #pragma unroll
    for (int j = 0; j < 8; j++) h1[j] = fmaxf(0.f, fmaf(ts, te_w1[j], te_b1[j]));

    float o[8];
    #pragma unroll
    for (int j = 0; j < 8; j++) {
        float v = te_b2[j];
        #pragma unroll
        for (int k = 0; k < 8; k++) v = fmaf(h1[k], te_w2[k*8 + j], v);
        o[j] = v;
    }
    float4* ob = reinterpret_cast<float4*>(&out[(size_t)idx * 8]);
    ob[0] = make_float4(o[0], o[1], o[2], o[3]);
    ob[1] = make_float4(o[4], o[5], o[6], o[7]);
}

// ---------------- two-pass chunked scan (f32 out)
template<int EMIT>
__global__ __launch_bounds__(512)
void scan_pass(const float* __restrict__ x, const float* __restrict__ t,
               const float* __restrict__ te_w1, const float* __restrict__ te_b1,
               const float* __restrict__ te_w2, const float* __restrict__ te_b2,
               float* __restrict__ ws, float* __restrict__ out) {
    const int c = blockIdx.x;      // chunk (walk order)
    const int b = blockIdx.y;      // batch
    const int d = blockIdx.z;      // 0 fwd, 1 bwd
    const int h = threadIdx.x;     // 0..511

    float wz[KIN], wh[KIN];
    #pragma unroll
    for (int i = 0; i < KIN; i++) {
        wz[i] = ws[WOFF_WEFF + ((2*d    )*KIN + i)*HH + h];
        wh[i] = ws[WOFF_WEFF + ((2*d + 1)*KIN + i)*HH + h];
    }
    float bz = ws[WOFF_BEFF + (2*d    )*HH + h];
    float bh = ws[WOFF_BEFF + (2*d + 1)*HH + h];

    __shared__ float w2s[64], w1s[8], b1s[8], b2s[8];
    __shared__ float xcs[CHK * KIN];
    if (threadIdx.x < 64) w2s[threadIdx.x] = te_w2[threadIdx.x];
    if (threadIdx.x < 8) {
        w1s[threadIdx.x] = te_w1[threadIdx.x];
        b1s[threadIdx.x] = te_b1[threadIdx.x];
        b2s[threadIdx.x] = te_b2[threadIdx.x];
    }
    __syncthreads();

    const int t0 = (d == 0) ? c * CHK : LSEQ - (c + 1) * CHK;
    if (threadIdx.x < CHK) {
        const size_t gi = (size_t)b * LSEQ + t0 + threadIdx.x;
        float ts = t[gi] - t[(size_t)b * LSEQ];
        float h1[8];
        #pragma unroll
        for (int j = 0; j < 8; j++) h1[j] = fmaxf(0.f, fmaf(ts, w1s[j], b1s[j]));
        float* xr = &xcs[threadIdx.x * KIN];
        float2 xv = reinterpret_cast<const float2*>(x)[gi];
        xr[0] = xv.x;
        xr[1] = xv.y;
        #pragma unroll
        for (int j = 0; j < 8; j++) {
            float v = b2s[j];
            #pragma unroll
            for (int k = 0; k < 8; k++) v = fmaf(h1[k], w2s[k*8 + j], v);
            xr[2 + j] = v;
        }
    }
    __syncthreads();

    float Hacc = 0.f, Pr = 1.f;
    if (EMIT) {   // fold carries of earlier-in-walk chunks
        const float* sg = ws + WOFF_SG + (size_t)((d*BB + b)*NC)*HH + h;
        const float* sp = ws + WOFF_SP + (size_t)((d*BB + b)*NC)*HH + h;
        for (int cc = 0; cc < c; cc++) {
            Hacc = fmaf(Pr, sg[(size_t)cc*HH], Hacc);
            Pr  *= sp[(size_t)cc*HH];
        }
    }

    float* ob = out + OUT_TENC_N + (size_t)d * HSIZE + (size_t)b * LSEQ * HH + h;
    for (int tt = 0; tt < CHK; tt++) {
        const int row = (d == 0) ? tt : (CHK - 1 - tt);    // bwd walks time descending
        const float* xr = &xcs[row * KIN];
        float zp = bz, hp = bh;
        #pragma unroll
        for (int i = 0; i < KIN; i++) {
            zp = fmaf(xr[i], wz[i], zp);
            hp = fmaf(xr[i], wh[i], hp);
        }
        float z = __builtin_amdgcn_rcpf(1.f + __expf(-zp));   // sigmoid
        if (EMIT)
            ob[(size_t)(t0 + row) * HH] = Hacc;   // emit BEFORE update = one-step shift
        Hacc = fmaf(Pr, z * hp, Hacc);
        Pr *= (1.f - z);
    }

    if (!EMIT) {
        ws[WOFF_SG + (size_t)((d*BB + b)*NC + c)*HH + h] = Hacc;
        ws[WOFF_SP + (size_t)((d*BB + b)*NC + c)*HH + h] = Pr;
    }
}

// ---------------- serial fallback (no ws), f32 out
__global__ __launch_bounds__(256)
void scan_serial(const float* __restrict__ x, const float* __restrict__ t,
                 const float* __restrict__ te_w1, const float* __restrict__ te_b1,
                 const float* __restrict__ te_w2, const float* __restrict__ te_b2,
                 const float* __restrict__ PWf, const float* __restrict__ PBf,
                 const float* __restrict__ PWb, const float* __restrict__ PBb,
                 const float* __restrict__ f_wz, const float* __restrict__ f_bz,
                 const float* __restrict__ f_wh, const float* __restrict__ f_bh,
                 const float* __restrict__ b_wz, const float* __restrict__ b_bz,
                 const float* __restrict__ b_wh, const float* __restrict__ b_bh,
                 float* __restrict__ out) {
    const int hg = blockIdx.x, b = blockIdx.y, d = blockIdx.z;
    const int h = hg * 256 + threadIdx.x;
    const float* PW = d ? PWb : PWf;   const float* PB = d ? PBb : PBf;
    const float* WZ = d ? b_wz : f_wz; const float* BZ = d ? b_bz : f_bz;
    const float* WH = d ? b_wh : f_wh; const float* BH = d ? b_bh : f_bh;

    float wz[KIN], wh[KIN];
    #pragma unroll
    for (int i = 0; i < KIN; i++) { wz[i] = 0.f; wh[i] = 0.f; }
    float bz = BZ[h], bh = BH[h];
    for (int k = 0; k < HH; k++) {
        float vz = WZ[k*HH + h], vh = WH[k*HH + h], pbk = PB[k];
        bz = fmaf(pbk, vz, bz);  bh = fmaf(pbk, vh, bh);
        #pragma unroll
        for (int i = 0; i < KIN; i++) {
            wz[i] = fmaf(PW[i*HH + k], vz, wz[i]);
            wh[i] = fmaf(PW[i*HH + k], vh, wh[i]);
        }
    }
    __shared__ float w2s[64], w1s[8], b1s[8], b2s[8], xcs[256*KIN];
    if (threadIdx.x < 64) w2s[threadIdx.x] = te_w2[threadIdx.x];
    if (threadIdx.x < 8) {
        w1s[threadIdx.x] = te_w1[threadIdx.x];
        b1s[threadIdx.x] = te_b1[threadIdx.x];
        b2s[threadIdx.x] = te_b2[threadIdx.x];
    }
    const float t_b0 = t[(size_t)b * LSEQ];
    float Hacc = 0.f, Pr = 1.f;
    float* ob = out + OUT_TENC_N + (size_t)d*HSIZE + (size_t)b*LSEQ*HH + h;
    for (int cc = 0; cc < LSEQ/256; cc++) {
        const int t0 = (d == 0) ? cc*256 : LSEQ - (cc+1)*256;
        __syncthreads();
        {
            const size_t gi = (size_t)b*LSEQ + t0 + threadIdx.x;
            float ts = t[gi] - t_b0;
            float h1[8];
            #pragma unroll
            for (int j = 0; j < 8; j++) h1[j] = fmaxf(0.f, fmaf(ts, w1s[j], b1s[j]));
            float* xr = &xcs[threadIdx.x * KIN];
            float2 xv = reinterpret_cast<const float2*>(x)[gi];
            xr[0] = xv.x; xr[1] = xv.y;
            #pragma unroll
            for (int j = 0; j < 8; j++) {
                float v = b2s[j];
                #pragma unroll
                for (int k = 0; k < 8; k++) v = fmaf(h1[k], w2s[k*8+j], v);
                xr[2+j] = v;
            }
        }
        __syncthreads();
        for (int tt = 0; tt < 256; tt++) {
            const int row = (d == 0) ? tt : (255 - tt);
            const float* xr = &xcs[row * KIN];
            float zp = bz, hp = bh;
            #pragma unroll
            for (int i = 0; i < KIN; i++) { zp = fmaf(xr[i], wz[i], zp); hp = fmaf(xr[i], wh[i], hp); }
            float z = __builtin_amdgcn_rcpf(1.f + __expf(-zp));
            ob[(size_t)(t0 + row) * HH] = Hacc;
            Hacc = fmaf(Pr, z * hp, Hacc);
            Pr *= (1.f - z);
        }
    }
}

extern "C" void kernel_launch(void* const* d_in, const int* in_sizes, int n_in,
                              void* d_out, int out_size, void* d_ws, size_t ws_size,
                              hipStream_t stream) {
    const float* x       = (const float*)d_in[0];
    const float* t       = (const float*)d_in[1];
    const float* te_w1   = (const float*)d_in[2];
    const float* te_b1   = (const float*)d_in[3];
    const float* te_w2   = (const float*)d_in[4];
    const float* te_b2   = (const float*)d_in[5];
    const float* fproj_w = (const float*)d_in[6];
    const float* fproj_b = (const float*)d_in[7];
    const float* bproj_w = (const float*)d_in[8];
    const float* bproj_b = (const float*)d_in[9];
    const float* f_wz    = (const float*)d_in[10];
    const float* f_bz    = (const float*)d_in[11];
    const float* f_wh    = (const float*)d_in[12];
    const float* f_bh    = (const float*)d_in[13];
    const float* b_wz    = (const float*)d_in[14];
    const float* b_bz    = (const float*)d_in[15];
    const float* b_wh    = (const float*)d_in[16];
    const float* b_bh    = (const float*)d_in[17];
    float* out           = (float*)d_out;     // reference outputs are float32
    float* ws            = (float*)d_ws;

    tenc_kernel<<<(BB*LSEQ)/256, 256, 0, stream>>>(t, te_w1, te_b1, te_w2, te_b2, out);

    if (ws_size >= (size_t)WS_FLOATS * sizeof(float)) {
        compose_kernel<<<4, 512, 0, stream>>>(fproj_w, fproj_b, bproj_w, bproj_b,
                                              f_wz, f_bz, f_wh, f_bh,
                                              b_wz, b_bz, b_wh, b_bh, ws);
        dim3 g(NC, BB, 2);
        scan_pass<0><<<g, 512, 0, stream>>>(x, t, te_w1, te_b1, te_w2, te_b2, ws, out);
        scan_pass<1><<<g, 512, 0, stream>>>(x, t, te_w1, te_b1, te_w2, te_b2, ws, out);
    } else {
        dim3 g(2, BB, 2);
        scan_serial<<<g, 256, 0, stream>>>(x, t, te_w1, te_b1, te_w2, te_b2,
                                           fproj_w, fproj_b, bproj_w, bproj_b,
                                           f_wz, f_bz, f_wh, f_bh,
                                           b_wz, b_bz, b_wh, b_bh, out);
    }
}

// Round 8
// 261.947 us; speedup vs baseline: 1.3888x; 1.3888x over previous
//
#include <hip/hip_runtime.h>
#include <hip/hip_bf16.h>
#include <stdint.h>

#define BB   8
#define LSEQ 4096
#define HH   512
#define KIN  10
#define NC   32
#define CHK  128       // LSEQ / NC
#define KT   16        // k-tiles for compose stage 1
#define KC   (HH/KT)   // 32 k per tile
#define XPAD 12        // xc padded stride (48 B -> 16B-aligned rows)

// f32 output layout (elements): t_enc [0, 262144), h_fwd, h_bwd
#define OUT_TENC_N (BB*LSEQ*8)
#define HSIZE      ((size_t)BB*LSEQ*HH)

// ws layout (floats):
//   [0, 20480)           Weff[4][KIN][HH]   m: 0=f_z 1=f_h 2=b_z 3=b_h
//   [20480, 22528)       beff[4][HH]
//   [22528, +262144)     sumG[2][BB][NC][HH]      (also reused for compose partials)
//   [.., +262144)        sumP[2][BB][NC][HH]
//   [546816, +393216)    xc[BB][LSEQ][XPAD]
#define WOFF_WEFF 0
#define WOFF_BEFF 20480
#define WOFF_SG   22528
#define WOFF_SP   (WOFF_SG + 2*BB*NC*HH)          // 22528 + 262144
#define WOFF_XC   (WOFF_SP + 2*BB*NC*HH)          // 546816
#define WS_FLOATS (WOFF_XC + BB*LSEQ*XPAD)        // 940032 floats = 3.59 MB
// compose partials (inside SG/SP region, dead once compose2 finishes):
#define POFF_W    WOFF_SG                          // [4*KT][KIN][HH] = 327680
#define POFF_B    (WOFF_SG + 4*KT*KIN*HH)          // [4*KT][HH]      = 32768

// ---------------- compose stage 1: per-(m, ktile) partial sums
__global__ __launch_bounds__(512)
void compose1(const float* __restrict__ fproj_w, const float* __restrict__ fproj_b,
              const float* __restrict__ bproj_w, const float* __restrict__ bproj_b,
              const float* __restrict__ f_wz, const float* __restrict__ f_wh,
              const float* __restrict__ b_wz, const float* __restrict__ b_wh,
              float* __restrict__ ws) {
    const int m  = blockIdx.x;       // 0=f_z 1=f_h 2=b_z 3=b_h
    const int kt = blockIdx.y;       // 0..KT-1
    const int j  = threadIdx.x;      // 0..511
    const float* P  = (m < 2) ? fproj_w : bproj_w;
    const float* pb = (m < 2) ? fproj_b : bproj_b;
    const float* W  = (m == 0) ? f_wz : (m == 1) ? f_wh : (m == 2) ? b_wz : b_wh;

    float acc[KIN];
    #pragma unroll
    for (int i = 0; i < KIN; i++) acc[i] = 0.f;
    float accb = 0.f;
    #pragma unroll 4
    for (int kk = 0; kk < KC; kk++) {
        const int k = kt * KC + kk;
        float w = W[(size_t)k*HH + j];            // coalesced
        accb = fmaf(pb[k], w, accb);              // uniform (s_load)
        #pragma unroll
        for (int i = 0; i < KIN; i++) acc[i] = fmaf(P[(size_t)i*HH + k], w, acc[i]);
    }
    const int mt = m*KT + kt;
    #pragma unroll
    for (int i = 0; i < KIN; i++) ws[POFF_W + ((size_t)mt*KIN + i)*HH + j] = acc[i];
    ws[POFF_B + (size_t)mt*HH + j] = accb;
}

// ---------------- compose stage 2: reduce partials + bias
__global__ __launch_bounds__(512)
void compose2(const float* __restrict__ f_bz, const float* __restrict__ f_bh,
              const float* __restrict__ b_bz, const float* __restrict__ b_bh,
              float* __restrict__ ws) {
    const int m = blockIdx.x, j = threadIdx.x;
    const float* wb = (m == 0) ? f_bz : (m == 1) ? f_bh : (m == 2) ? b_bz : b_bh;
    #pragma unroll
    for (int i = 0; i < KIN; i++) {
        float s = 0.f;
        #pragma unroll
        for (int kt = 0; kt < KT; kt++)
            s += ws[POFF_W + ((size_t)(m*KT + kt)*KIN + i)*HH + j];
        ws[WOFF_WEFF + (m*KIN + i)*HH + j] = s;
    }
    float sb = wb[j];
    #pragma unroll
    for (int kt = 0; kt < KT; kt++) sb += ws[POFF_B + (size_t)(m*KT + kt)*HH + j];
    ws[WOFF_BEFF + m*HH + j] = sb;
}

// ---------------- xc + t_enc: one thread per timestep
__global__ __launch_bounds__(256)
void xc_kernel(const float* __restrict__ x, const float* __restrict__ t,
               const float* __restrict__ te_w1, const float* __restrict__ te_b1,
               const float* __restrict__ te_w2, const float* __restrict__ te_b2,
               float* __restrict__ ws, float* __restrict__ out) {
    const int idx = blockIdx.x * 256 + threadIdx.x;   // b*L + l
    const int b = idx >> 12;
    float ts = t[idx] - t[(size_t)b << 12];

    float h1[8];
    #pragma unroll
    for (int j = 0; j < 8; j++) h1[j] = fmaxf(0.f, fmaf(ts, te_w1[j], te_b1[j]));

    float o[8];
    #pragma unroll
    for (int j = 0; j < 8; j++) {
        float v = te_b2[j];
        #pragma unroll
        for (int k = 0; k < 8; k++) v = fmaf(h1[k], te_w2[k*8 + j], v);
        o[j] = v;
    }
    // t_enc output (f32)
    float4* ob = reinterpret_cast<float4*>(&out[(size_t)idx * 8]);
    ob[0] = make_float4(o[0], o[1], o[2], o[3]);
    ob[1] = make_float4(o[4], o[5], o[6], o[7]);
    // xc row (padded to 12)
    float2 xv = reinterpret_cast<const float2*>(x)[idx];
    float4* xb = reinterpret_cast<float4*>(&ws[WOFF_XC + (size_t)idx * XPAD]);
    xb[0] = make_float4(xv.x, xv.y, o[0], o[1]);
    xb[1] = make_float4(o[2], o[3], o[4], o[5]);
    xb[2] = make_float4(o[6], o[7], 0.f, 0.f);
}

// ---------------- scan: no LDS, xc via uniform scalar loads
template<int EMIT>
__global__ __launch_bounds__(512)
void scan2(const float* __restrict__ weff, const float* __restrict__ beff,
           const float* __restrict__ xc,
           float* __restrict__ sg, float* __restrict__ sp,
           float* __restrict__ out) {
    const int c = blockIdx.x;      // chunk (walk order)
    const int b = blockIdx.y;      // batch
    const int d = blockIdx.z;      // 0 fwd, 1 bwd
    const int h = threadIdx.x;     // 0..511

    float wz[KIN], wh[KIN];
    #pragma unroll
    for (int i = 0; i < KIN; i++) {
        wz[i] = weff[((2*d    )*KIN + i)*HH + h];
        wh[i] = weff[((2*d + 1)*KIN + i)*HH + h];
    }
    float bz = beff[(2*d    )*HH + h];
    float bh = beff[(2*d + 1)*HH + h];

    const int t0 = (d == 0) ? c * CHK : LSEQ - (c + 1) * CHK;
    const float* __restrict__ xr = xc + ((size_t)b * LSEQ + t0) * XPAD;

    float Hacc = 0.f, Pr = 1.f;
    if (EMIT) {   // fold carries of earlier-in-walk chunks
        const float* g = sg + (size_t)((d*BB + b)*NC)*HH + h;
        const float* p = sp + (size_t)((d*BB + b)*NC)*HH + h;
        for (int cc = 0; cc < c; cc++) {
            Hacc = fmaf(Pr, g[(size_t)cc*HH], Hacc);
            Pr  *= p[(size_t)cc*HH];
        }
    }

    float* ob = out + OUT_TENC_N + (size_t)d * HSIZE + (size_t)b * LSEQ * HH + h;
    for (int tt = 0; tt < CHK; tt++) {
        const int row = (d == 0) ? tt : (CHK - 1 - tt);   // bwd walks time descending
        const float* q = xr + row * XPAD;                 // uniform address -> s_load
        float zp = bz, hp = bh;
        #pragma unroll
        for (int i = 0; i < KIN; i++) {
            float v = q[i];
            zp = fmaf(v, wz[i], zp);
            hp = fmaf(v, wh[i], hp);
        }
        float z = __builtin_amdgcn_rcpf(1.f + __expf(-zp));   // sigmoid
        if (EMIT)
            ob[(size_t)(t0 + row) * HH] = Hacc;   // emit BEFORE update = one-step shift
        Hacc = fmaf(Pr, z * hp, Hacc);
        Pr *= (1.f - z);
    }

    if (!EMIT) {
        sg[(size_t)((d*BB + b)*NC + c)*HH + h] = Hacc;
        sp[(size_t)((d*BB + b)*NC + c)*HH + h] = Pr;
    }
}

// ---------------- serial fallback (no ws) — safety net only
__global__ __launch_bounds__(256)
void scan_serial(const float* __restrict__ x, const float* __restrict__ t,
                 const float* __restrict__ te_w1, const float* __restrict__ te_b1,
                 const float* __restrict__ te_w2, const float* __restrict__ te_b2,
                 const float* __restrict__ PWf, const float* __restrict__ PBf,
                 const float* __restrict__ PWb, const float* __restrict__ PBb,
                 const float* __restrict__ f_wz, const float* __restrict__ f_bz,
                 const float* __restrict__ f_wh, const float* __restrict__ f_bh,
                 const float* __restrict__ b_wz, const float* __restrict__ b_bz,
                 const float* __restrict__ b_wh, const float* __restrict__ b_bh,
                 float* __restrict__ out) {
    const int hg = blockIdx.x, b = blockIdx.y, d = blockIdx.z;
    const int h = hg * 256 + threadIdx.x;
    const float* PW = d ? PWb : PWf;   const float* PB = d ? PBb : PBf;
    const float* WZ = d ? b_wz : f_wz; const float* BZ = d ? b_bz : f_bz;
    const float* WH = d ? b_wh : f_wh; const float* BH = d ? b_bh : f_bh;

    float wz[KIN], wh[KIN];
    #pragma unroll
    for (int i = 0; i < KIN; i++) { wz[i] = 0.f; wh[i] = 0.f; }
    float bz = BZ[h], bh = BH[h];
    for (int k = 0; k < HH; k++) {
        float vz = WZ[k*HH + h], vh = WH[k*HH + h], pbk = PB[k];
        bz = fmaf(pbk, vz, bz);  bh = fmaf(pbk, vh, bh);
        #pragma unroll
        for (int i = 0; i < KIN; i++) {
            wz[i] = fmaf(PW[i*HH + k], vz, wz[i]);
            wh[i] = fmaf(PW[i*HH + k], vh, wh[i]);
        }
    }
    __shared__ float w2s[64], w1s[8], b1s[8], b2s[8], xcs[256*KIN];
    if (threadIdx.x < 64) w2s[threadIdx.x] = te_w2[threadIdx.x];
    if (threadIdx.x < 8) {
        w1s[threadIdx.x] = te_w1[threadIdx.x];
        b1s[threadIdx.x] = te_b1[threadIdx.x];
        b2s[threadIdx.x] = te_b2[threadIdx.x];
    }
    const float t_b0 = t[(size_t)b * LSEQ];
    float Hacc = 0.f, Pr = 1.f;
    float* ob = out + OUT_TENC_N + (size_t)d*HSIZE + (size_t)b*LSEQ*HH + h;
    for (int cc = 0; cc < LSEQ/256; cc++) {
        const int t0 = (d == 0) ? cc*256 : LSEQ - (cc+1)*256;
        __syncthreads();
        {
            const size_t gi = (size_t)b*LSEQ + t0 + threadIdx.x;
            float ts = t[gi] - t_b0;
            float h1[8];
            #pragma unroll
            for (int j = 0; j < 8; j++) h1[j] = fmaxf(0.f, fmaf(ts, w1s[j], b1s[j]));
            float* xr = &xcs[threadIdx.x * KIN];
            float2 xv = reinterpret_cast<const float2*>(x)[gi];
            xr[0] = xv.x; xr[1] = xv.y;
            #pragma unroll
            for (int j = 0; j < 8; j++) {
                float v = b2s[j];
                #pragma unroll
                for (int k = 0; k < 8; k++) v = fmaf(h1[k], w2s[k*8+j], v);
                xr[2+j] = v;
            }
        }
        __syncthreads();
        for (int tt = 0; tt < 256; tt++) {
            const int row = (d == 0) ? tt : (255 - tt);
            const float* xr = &xcs[row * KIN];
            float zp = bz, hp = bh;
            #pragma unroll
            for (int i = 0; i < KIN; i++) { zp = fmaf(xr[i], wz[i], zp); hp = fmaf(xr[i], wh[i], hp); }
            float z = __builtin_amdgcn_rcpf(1.f + __expf(-zp));
            ob[(size_t)(t0 + row) * HH] = Hacc;
            Hacc = fmaf(Pr, z * hp, Hacc);
            Pr *= (1.f - z);
        }
    }
}

__global__ __launch_bounds__(256)
void tenc_fb(const float* __restrict__ t,
             const float* __restrict__ te_w1, const float* __restrict__ te_b1,
             const float* __restrict__ te_w2, const float* __restrict__ te_b2,
             float* __restrict__ out) {
    int idx = blockIdx.x * 256 + threadIdx.x;
    int b = idx >> 12;
    float ts = t[idx] - t[(size_t)b << 12];
    float h1[8];
    #pragma unroll
    for (int j = 0; j < 8; j++) h1[j] = fmaxf(0.f, fmaf(ts, te_w1[j], te_b1[j]));
    float o[8];
    #pragma unroll
    for (int j = 0; j < 8; j++) {
        float v = te_b2[j];
        #pragma unroll
        for (int k = 0; k < 8; k++) v = fmaf(h1[k], te_w2[k*8 + j], v);
        o[j] = v;
    }
    float4* ob = reinterpret_cast<float4*>(&out[(size_t)idx * 8]);
    ob[0] = make_float4(o[0], o[1], o[2], o[3]);
    ob[1] = make_float4(o[4], o[5], o[6], o[7]);
}

extern "C" void kernel_launch(void* const* d_in, const int* in_sizes, int n_in,
                              void* d_out, int out_size, void* d_ws, size_t ws_size,
                              hipStream_t stream) {
    const float* x       = (const float*)d_in[0];
    const float* t       = (const float*)d_in[1];
    const float* te_w1   = (const float*)d_in[2];
    const float* te_b1   = (const float*)d_in[3];
    const float* te_w2   = (const float*)d_in[4];
    const float* te_b2   = (const float*)d_in[5];
    const float* fproj_w = (const float*)d_in[6];
    const float* fproj_b = (const float*)d_in[7];
    const float* bproj_w = (const float*)d_in[8];
    const float* bproj_b = (const float*)d_in[9];
    const float* f_wz    = (const float*)d_in[10];
    const float* f_bz    = (const float*)d_in[11];
    const float* f_wh    = (const float*)d_in[12];
    const float* f_bh    = (const float*)d_in[13];
    const float* b_wz    = (const float*)d_in[14];
    const float* b_bz    = (const float*)d_in[15];
    const float* b_wh    = (const float*)d_in[16];
    const float* b_bh    = (const float*)d_in[17];
    float* out           = (float*)d_out;     // outputs are float32
    float* ws            = (float*)d_ws;

    if (ws_size >= (size_t)WS_FLOATS * sizeof(float)) {
        xc_kernel<<<(BB*LSEQ)/256, 256, 0, stream>>>(x, t, te_w1, te_b1, te_w2, te_b2, ws, out);
        dim3 gc(4, KT);
        compose1<<<gc, 512, 0, stream>>>(fproj_w, fproj_b, bproj_w, bproj_b,
                                         f_wz, f_wh, b_wz, b_wh, ws);
        compose2<<<4, 512, 0, stream>>>(f_bz, f_bh, b_bz, b_bh, ws);

        dim3 g(NC, BB, 2);
        scan2<0><<<g, 512, 0, stream>>>(ws + WOFF_WEFF, ws + WOFF_BEFF, ws + WOFF_XC,
                                        ws + WOFF_SG, ws + WOFF_SP, out);
        scan2<1><<<g, 512, 0, stream>>>(ws + WOFF_WEFF, ws + WOFF_BEFF, ws + WOFF_XC,
                                        ws + WOFF_SG, ws + WOFF_SP, out);
    } else {
        tenc_fb<<<(BB*LSEQ)/256, 256, 0, stream>>>(t, te_w1, te_b1, te_w2, te_b2, out);
        dim3 g(2, BB, 2);
        scan_serial<<<g, 256, 0, stream>>>(x, t, te_w1, te_b1, te_w2, te_b2,
                                           fproj_w, fproj_b, bproj_w, bproj_b,
                                           f_wz, f_bz, f_wh, f_bh,
                                           b_wz, b_bz, b_wh, b_bh, out);
    }
}